// Round 10
// baseline (904.866 us; speedup 1.0000x reference)
//
#include <hip/hip_runtime.h>
#include <cmath>

#define NB 8
#define NN 20000
#define ND 128
#define NE_TOT 192000   /* 3 edge sets * 64000 edges, contiguous per batch */

#define RSZ 128                     /* nodes per src-range */
#define NR 157                      /* ceil(NN / RSZ) */
#define CAP 2048                    /* bucket capacity; avg fill 1223 */
#define ECHUNK 8000                 /* edges per bucketing chunk */
#define NCHUNK 24                   /* NE_TOT / ECHUNK, exact */

#define GR 5                        /* ranges per pass block */
#define NCG 32                      /* range-groups: NCG*GR=160 >= NR */

#define REPS 16                     /* bench replica count */

// weight ping-pong + bucket metadata + buckets + pool partials
__device__ float g_w0[NB * NN];
__device__ float g_w1[NB * NN];
__device__ int   g_bcnt[NB][NCHUNK][NR];
__device__ int   g_cnt[NB * NR];
__device__ int2  g_bucket[(size_t)NB * NR * CAP];   // 20.6 MB
__device__ float g_ppart[NB * NCG * ND];            // 128 KB

// dummy sinks for bench replicas (never read by the real pipeline)
__device__ float g_wdummy[NB * NN];
__device__ int   g_bcnt_dummy[NB][NCHUNK][NR];
__device__ int2  g_bucket_dummy[(size_t)NB * NR * CAP];
__device__ float g_ppart_dummy[NB * NCG * ND];

// ---- kernel 1: w0 = 1  +  per-(batch,chunk) src-range histograms ----
__global__ void initCountK(const int* __restrict__ edges) {
    __shared__ int hist[NR];
    const int b = blockIdx.x / NCHUNK, c = blockIdx.x % NCHUNK;
    const int t = threadIdx.x;  // 256

    for (int i = blockIdx.x * 256 + t; i < NB * NN; i += NB * NCHUNK * 256)
        g_w0[i] = 1.0f;

    for (int i = t; i < NR; i += 256) hist[i] = 0;
    __syncthreads();
    const int2* __restrict__ ep =
        (const int2*)edges + (size_t)b * NE_TOT + (size_t)c * ECHUNK;
    for (int i = t; i < ECHUNK; i += 256)
        atomicAdd(&hist[ep[i].y >> 7], 1);
    __syncthreads();
    for (int i = t; i < NR; i += 256) g_bcnt[b][c][i] = hist[i];
}

// ---- kernel 2: distribute edges; each block derives its own prefix offset ----
__global__ void distK(const int* __restrict__ edges) {
    __shared__ int cur[NR];
    const int b = blockIdx.x / NCHUNK, c = blockIdx.x % NCHUNK;
    const int t = threadIdx.x;  // 256
    for (int r = t; r < NR; r += 256) {
        int off = 0;
        for (int cc = 0; cc < c; ++cc) off += g_bcnt[b][cc][r];
        cur[r] = off;
        if (c == NCHUNK - 1) g_cnt[b * NR + r] = off + g_bcnt[b][c][r];
    }
    __syncthreads();
    const int2* __restrict__ ep =
        (const int2*)edges + (size_t)b * NE_TOT + (size_t)c * ECHUNK;
    for (int i = t; i < ECHUNK; i += 256) {
        const int2 e = ep[i];             // e.x = dst, e.y = src
        const int r = e.y >> 7;
        const int pos = atomicAdd(&cur[r], 1);
        if (pos < CAP)
            g_bucket[((size_t)b * NR + r) * CAP + pos] = make_int2(e.x, e.y & (RSZ - 1));
    }
}

// ---- kernels 3-6: one pass, full w staged in LDS ----
__global__ void __launch_bounds__(1024)
passLDSK(int sel) {
    extern __shared__ float w_lds[];      // NN floats = 80 KB (dynamic)
    __shared__ float acc[GR * RSZ];       // 2.5 KB
    const int b  = blockIdx.y;
    const int r0 = blockIdx.x * GR;
    const int gr = min(GR, NR - r0);
    const int t  = threadIdx.x;           // 1024
    const float* __restrict__ w  = sel ? g_w1 : g_w0;
    float* __restrict__ wn       = sel ? g_w0 : g_w1;
    const float* __restrict__ wb = w + b * NN;

    const float4* __restrict__ wb4 = (const float4*)wb;
    for (int i = t; i < NN / 4; i += 1024) ((float4*)w_lds)[i] = wb4[i];
    if (t < GR * RSZ) acc[t] = 0.0f;
    __syncthreads();

    for (int rr = 0; rr < gr; ++rr) {
        const int u = b * NR + r0 + rr;
        const int cnt = g_cnt[u];
        const int2* __restrict__ bk = g_bucket + (size_t)u * CAP;
        float* accr = acc + rr * RSZ;
        for (int i = t; i < cnt; i += 1024) {
            const int2 e = bk[i];
            unsafeAtomicAdd(&accr[e.y], w_lds[e.x]);
        }
    }
    __syncthreads();

    for (int i = t; i < gr * RSZ; i += 1024) {
        const int node = r0 * RSZ + i;
        if (node < NN) wn[b * NN + node] = w_lds[node] + acc[i];
    }
}

// ---- kernel 7: final pass fused with weighted pool ----
__global__ void __launch_bounds__(1024)
pass5poolK(const float* __restrict__ nodes) {
    extern __shared__ float w_lds[];
    __shared__ float acc[GR * RSZ];
    __shared__ float w5s[GR * RSZ];
    const int b  = blockIdx.y;
    const int r0 = blockIdx.x * GR;
    const int gr = min(GR, NR - r0);
    const int t  = threadIdx.x;           // 1024
    const float* __restrict__ wb = g_w0 + b * NN;   // w4 lives in g_w0

    const float4* __restrict__ wb4 = (const float4*)wb;
    for (int i = t; i < NN / 4; i += 1024) ((float4*)w_lds)[i] = wb4[i];
    if (t < GR * RSZ) acc[t] = 0.0f;
    __syncthreads();

    for (int rr = 0; rr < gr; ++rr) {
        const int u = b * NR + r0 + rr;
        const int cnt = g_cnt[u];
        const int2* __restrict__ bk = g_bucket + (size_t)u * CAP;
        float* accr = acc + rr * RSZ;
        for (int i = t; i < cnt; i += 1024) {
            const int2 e = bk[i];
            unsafeAtomicAdd(&accr[e.y], w_lds[e.x]);
        }
    }
    __syncthreads();

    if (t < GR * RSZ) {
        const int node = r0 * RSZ + t;
        w5s[t] = (t < gr * RSZ && node < NN) ? w_lds[node] + acc[t] : 0.0f;
    }
    __syncthreads();

    const int dslot = t & 31, rg = t >> 5;
    const int nbase = r0 * RSZ;
    const int nrows = min(GR * RSZ, NN - nbase);
    const float4* __restrict__ base = (const float4*)(nodes + (size_t)b * NN * ND);
    float4 aA = {0.f, 0.f, 0.f, 0.f}, aB = {0.f, 0.f, 0.f, 0.f};
    int row = rg;
    for (; row + 32 < nrows; row += 64) {
        const float wA = w5s[row], wB = w5s[row + 32];
        const float4 vA = base[(size_t)(nbase + row) * 32 + dslot];
        const float4 vB = base[(size_t)(nbase + row + 32) * 32 + dslot];
        aA.x += wA * vA.x; aA.y += wA * vA.y; aA.z += wA * vA.z; aA.w += wA * vA.w;
        aB.x += wB * vB.x; aB.y += wB * vB.y; aB.z += wB * vB.z; aB.w += wB * vB.w;
    }
    if (row < nrows) {
        const float wA = w5s[row];
        const float4 vA = base[(size_t)(nbase + row) * 32 + dslot];
        aA.x += wA * vA.x; aA.y += wA * vA.y; aA.z += wA * vA.z; aA.w += wA * vA.w;
    }
    float4 s4;
    s4.x = aA.x + aB.x; s4.y = aA.y + aB.y; s4.z = aA.z + aB.z; s4.w = aA.w + aB.w;

    __syncthreads();
    float4* red = (float4*)w_lds;
    red[t] = s4;
    __syncthreads();
    if (t < 32) {
        float4 s = red[t];
        for (int g = 1; g < 32; ++g) {
            const float4 o = red[g * 32 + t];
            s.x += o.x; s.y += o.y; s.z += o.z; s.w += o.w;
        }
        ((float4*)g_ppart)[((size_t)b * NCG + blockIdx.x) * 32 + t] = s;
    }
}

// ---- kernel 8: reduce partials + head ----
__global__ void reduceHeadK(const float* __restrict__ ptype,
                            const float* __restrict__ w1, const float* __restrict__ b1,
                            const float* __restrict__ w2, const float* __restrict__ b2,
                            const float* __restrict__ w3, const float* __restrict__ b3,
                            float* __restrict__ out) {
    __shared__ float sx[NB][ND + 1];
    __shared__ float h1s[NB][80];
    __shared__ float h2s[NB][80];
    const int t = threadIdx.x;          // 1024 == NB * ND
    const int b = t >> 7, d = t & 127;

    float s = 0.0f;
    for (int j = 0; j < NCG; ++j)
        s += g_ppart[(b * NCG + j) * ND + d];

    float y = logf(s);
    if (isnan(y)) y = 0.0f;
    y = fmaxf(y, 0.0f);
    sx[b][d] = y;
    __syncthreads();

    if (t < NB) {
        float fm = -INFINITY;
        for (int dd = 0; dd < ND; ++dd) {
            const float v = sx[t][dd];
            if (!isinf(v)) fm = fmaxf(fm, v);
        }
        for (int dd = 0; dd < ND; ++dd)
            if (isinf(sx[t][dd])) sx[t][dd] = fm;
        sx[t][ND] = ptype[t];
    }
    __syncthreads();

    if (t < NB * 80) {
        const int bb = t / 80, j = t - bb * 80;
        float v = b1[j];
        for (int k = 0; k < ND + 1; ++k) v += sx[bb][k] * w1[k * 80 + j];
        h1s[bb][j] = v > 0.0f ? v : 0.01f * v;
    }
    __syncthreads();

    if (t < NB * 80) {
        const int bb = t / 80, j = t - bb * 80;
        float v = b2[j];
        for (int k = 0; k < 80; ++k) v += h1s[bb][k] * w2[k * 80 + j];
        h2s[bb][j] = v > 0.0f ? v : 0.01f * v;
    }
    __syncthreads();

    if (t < NB * 10) {
        const int bb = t / 10, j = t - bb * 10;
        float v = b3[j];
        for (int k = 0; k < 80; ++k) v += h2s[bb][k] * w3[k * 10 + j];
        out[bb * 10 + j] = v;
    }
}

// ================= bench replicas (timing instrumentation only) =================
// Each repeats one real phase's exact body REPS times, writing dummy sinks.
// Run after the real pipeline; never touch real state or d_out.

__global__ void benchCountK(const int* __restrict__ edges) {
    __shared__ int hist[NR];
    const int b = blockIdx.x / NCHUNK, c = blockIdx.x % NCHUNK;
    const int t = threadIdx.x;
#pragma unroll 1
    for (int rep = 0; rep < REPS; ++rep) {
        for (int i = t; i < NR; i += 256) hist[i] = 0;
        __syncthreads();
        const int2* __restrict__ ep =
            (const int2*)edges + (size_t)b * NE_TOT + (size_t)c * ECHUNK;
        for (int i = t; i < ECHUNK; i += 256)
            atomicAdd(&hist[ep[i].y >> 7], 1);
        __syncthreads();
        for (int i = t; i < NR; i += 256) g_bcnt_dummy[b][c][i] = hist[i];
        __syncthreads();
        asm volatile("" ::: "memory");
    }
}

__global__ void benchDistK(const int* __restrict__ edges) {
    __shared__ int cur[NR];
    const int b = blockIdx.x / NCHUNK, c = blockIdx.x % NCHUNK;
    const int t = threadIdx.x;
#pragma unroll 1
    for (int rep = 0; rep < REPS; ++rep) {
        for (int r = t; r < NR; r += 256) {
            int off = 0;
            for (int cc = 0; cc < c; ++cc) off += g_bcnt[b][cc][r];
            cur[r] = off;
        }
        __syncthreads();
        const int2* __restrict__ ep =
            (const int2*)edges + (size_t)b * NE_TOT + (size_t)c * ECHUNK;
        for (int i = t; i < ECHUNK; i += 256) {
            const int2 e = ep[i];
            const int r = e.y >> 7;
            const int pos = atomicAdd(&cur[r], 1);
            if (pos < CAP)
                g_bucket_dummy[((size_t)b * NR + r) * CAP + pos] =
                    make_int2(e.x, e.y & (RSZ - 1));
        }
        __syncthreads();
        asm volatile("" ::: "memory");
    }
}

__global__ void __launch_bounds__(1024)
benchPassK() {
    extern __shared__ float w_lds[];
    __shared__ float acc[GR * RSZ];
    const int b  = blockIdx.y;
    const int r0 = blockIdx.x * GR;
    const int gr = min(GR, NR - r0);
    const int t  = threadIdx.x;
    const float* __restrict__ wb = g_w0 + b * NN;   // values irrelevant for timing
#pragma unroll 1
    for (int rep = 0; rep < REPS; ++rep) {
        const float4* __restrict__ wb4 = (const float4*)wb;
        for (int i = t; i < NN / 4; i += 1024) ((float4*)w_lds)[i] = wb4[i];
        if (t < GR * RSZ) acc[t] = 0.0f;
        __syncthreads();
        for (int rr = 0; rr < gr; ++rr) {
            const int u = b * NR + r0 + rr;
            const int cnt = g_cnt[u];
            const int2* __restrict__ bk = g_bucket + (size_t)u * CAP;
            float* accr = acc + rr * RSZ;
            for (int i = t; i < cnt; i += 1024) {
                const int2 e = bk[i];
                unsafeAtomicAdd(&accr[e.y], w_lds[e.x]);
            }
        }
        __syncthreads();
        for (int i = t; i < gr * RSZ; i += 1024) {
            const int node = r0 * RSZ + i;
            if (node < NN) g_wdummy[b * NN + node] = w_lds[node] + acc[i];
        }
        __syncthreads();
        asm volatile("" ::: "memory");
    }
}

__global__ void __launch_bounds__(1024)
benchPoolK(const float* __restrict__ nodes) {
    extern __shared__ float w_lds[];
    __shared__ float acc[GR * RSZ];
    __shared__ float w5s[GR * RSZ];
    const int b  = blockIdx.y;
    const int r0 = blockIdx.x * GR;
    const int gr = min(GR, NR - r0);
    const int t  = threadIdx.x;
    const float* __restrict__ wb = g_w0 + b * NN;
#pragma unroll 1
    for (int rep = 0; rep < REPS; ++rep) {
        const float4* __restrict__ wb4 = (const float4*)wb;
        for (int i = t; i < NN / 4; i += 1024) ((float4*)w_lds)[i] = wb4[i];
        if (t < GR * RSZ) acc[t] = 0.0f;
        __syncthreads();
        for (int rr = 0; rr < gr; ++rr) {
            const int u = b * NR + r0 + rr;
            const int cnt = g_cnt[u];
            const int2* __restrict__ bk = g_bucket + (size_t)u * CAP;
            float* accr = acc + rr * RSZ;
            for (int i = t; i < cnt; i += 1024) {
                const int2 e = bk[i];
                unsafeAtomicAdd(&accr[e.y], w_lds[e.x]);
            }
        }
        __syncthreads();
        if (t < GR * RSZ) {
            const int node = r0 * RSZ + t;
            w5s[t] = (t < gr * RSZ && node < NN) ? w_lds[node] + acc[t] : 0.0f;
        }
        __syncthreads();
        const int dslot = t & 31, rg = t >> 5;
        const int nbase = r0 * RSZ;
        const int nrows = min(GR * RSZ, NN - nbase);
        const float4* __restrict__ base = (const float4*)(nodes + (size_t)b * NN * ND);
        float4 aA = {0.f, 0.f, 0.f, 0.f}, aB = {0.f, 0.f, 0.f, 0.f};
        int row = rg;
        for (; row + 32 < nrows; row += 64) {
            const float wA = w5s[row], wB = w5s[row + 32];
            const float4 vA = base[(size_t)(nbase + row) * 32 + dslot];
            const float4 vB = base[(size_t)(nbase + row + 32) * 32 + dslot];
            aA.x += wA * vA.x; aA.y += wA * vA.y; aA.z += wA * vA.z; aA.w += wA * vA.w;
            aB.x += wB * vB.x; aB.y += wB * vB.y; aB.z += wB * vB.z; aB.w += wB * vB.w;
        }
        if (row < nrows) {
            const float wA = w5s[row];
            const float4 vA = base[(size_t)(nbase + row) * 32 + dslot];
            aA.x += wA * vA.x; aA.y += wA * vA.y; aA.z += wA * vA.z; aA.w += wA * vA.w;
        }
        float4 s4;
        s4.x = aA.x + aB.x; s4.y = aA.y + aB.y; s4.z = aA.z + aB.z; s4.w = aA.w + aB.w;
        __syncthreads();
        float4* red = (float4*)w_lds;
        red[t] = s4;
        __syncthreads();
        if (t < 32) {
            float4 s = red[t];
            for (int g = 1; g < 32; ++g) {
                const float4 o = red[g * 32 + t];
                s.x += o.x; s.y += o.y; s.z += o.z; s.w += o.w;
            }
            ((float4*)g_ppart_dummy)[((size_t)b * NCG + blockIdx.x) * 32 + t] = s;
        }
        __syncthreads();
        asm volatile("" ::: "memory");
    }
}

extern "C" void kernel_launch(void* const* d_in, const int* in_sizes, int n_in,
                              void* d_out, int out_size, void* d_ws, size_t ws_size,
                              hipStream_t stream) {
    const float* nodes = (const float*)d_in[0];
    const float* ptype = (const float*)d_in[1];
    const float* w1    = (const float*)d_in[2];
    const float* b1    = (const float*)d_in[3];
    const float* w2    = (const float*)d_in[4];
    const float* b2    = (const float*)d_in[5];
    const float* w3    = (const float*)d_in[6];
    const float* b3    = (const float*)d_in[7];
    const int*   edges = (const int*)d_in[8];
    float* out = (float*)d_out;

    // ---- real pipeline (unchanged from R9) ----
    initCountK<<<NB * NCHUNK, 256, 0, stream>>>(edges);
    distK<<<NB * NCHUNK, 256, 0, stream>>>(edges);
    passLDSK<<<dim3(NCG, NB), 1024, NN * sizeof(float), stream>>>(0);
    passLDSK<<<dim3(NCG, NB), 1024, NN * sizeof(float), stream>>>(1);
    passLDSK<<<dim3(NCG, NB), 1024, NN * sizeof(float), stream>>>(0);
    passLDSK<<<dim3(NCG, NB), 1024, NN * sizeof(float), stream>>>(1);
    pass5poolK<<<dim3(NCG, NB), 1024, NN * sizeof(float), stream>>>(nodes);
    reduceHeadK<<<1, 1024, 0, stream>>>(ptype, w1, b1, w2, b2, w3, b3, out);

    // ---- instrumentation: x16 replicas of each phase, dummy sinks ----
    benchCountK<<<NB * NCHUNK, 256, 0, stream>>>(edges);
    benchDistK<<<NB * NCHUNK, 256, 0, stream>>>(edges);
    benchPassK<<<dim3(NCG, NB), 1024, NN * sizeof(float), stream>>>();
    benchPoolK<<<dim3(NCG, NB), 1024, NN * sizeof(float), stream>>>(nodes);
}

// Round 11
// 130.123 us; speedup vs baseline: 6.9539x; 6.9539x over previous
//
#include <hip/hip_runtime.h>
#include <cmath>

#define NB 8
#define NN 20000
#define ND 128
#define NE_TOT 192000   /* 3 edge sets * 64000 edges, contiguous per batch */

#define GSZ 640                     /* src nodes per group */
#define NG 32                       /* NG*GSZ = 20480 >= NN; grid 32 x 8 */
#define FIX 8192                    /* padded entries per (b,g); = 8*1024 */
#define KPT 8                       /* FIX / 1024 = loads per thread */
#define ECHUNK 8000                 /* edges per bucketing chunk */
#define NCHUNK 24                   /* NE_TOT / ECHUNK, exact */

// weight ping-pong + bucket metadata + fixed-stride buckets + pool partials
__device__ float g_w0[NB * NN];
__device__ float g_w1[NB * NN];
__device__ int   g_bcnt[NB][NCHUNK][NG];
__device__ int   g_cnt[NB * NG];
__device__ int2  g_bucket[(size_t)NB * NG * FIX];   // 16.8 MB
__device__ float g_ppart[NB * NG * ND];             // 128 KB

// ---- kernel 1: per-(batch,chunk) histograms over the 32 src-groups ----
__global__ void countK(const int* __restrict__ edges) {
    __shared__ int hist[NG];
    const int b = blockIdx.x / NCHUNK, c = blockIdx.x % NCHUNK;
    const int t = threadIdx.x;  // 256
    if (t < NG) hist[t] = 0;
    __syncthreads();
    const int2* __restrict__ ep =
        (const int2*)edges + (size_t)b * NE_TOT + (size_t)c * ECHUNK;
    for (int i = t; i < ECHUNK; i += 256)
        atomicAdd(&hist[(unsigned)ep[i].y / GSZ], 1);
    __syncthreads();
    if (t < NG) g_bcnt[b][c][t] = hist[t];
}

// ---- kernel 2: distribute edges into fixed-stride buckets ----
__global__ void distK(const int* __restrict__ edges) {
    __shared__ int cur[NG];
    const int b = blockIdx.x / NCHUNK, c = blockIdx.x % NCHUNK;
    const int t = threadIdx.x;  // 256
    if (t < NG) {
        int off = 0;
        for (int cc = 0; cc < c; ++cc) off += g_bcnt[b][cc][t];
        cur[t] = off;
        if (c == NCHUNK - 1) g_cnt[b * NG + t] = off + g_bcnt[b][c][t];
    }
    __syncthreads();
    const int2* __restrict__ ep =
        (const int2*)edges + (size_t)b * NE_TOT + (size_t)c * ECHUNK;
    for (int i = t; i < ECHUNK; i += 256) {
        const int2 e = ep[i];                 // e.x = dst, e.y = src
        const unsigned g = (unsigned)e.y / GSZ;
        const int pos = atomicAdd(&cur[g], 1);
        if (pos < FIX)                        // +26 sigma guard
            g_bucket[((size_t)(b * NG + g)) * FIX + pos] =
                make_int2(e.x, e.y - (int)g * GSZ);
    }
}

// ---- one pass (w_next = w + A^T w): fixed-count early-issued loads ----
// FIRST: w == all-ones -> no staging, no ds_read, no init kernel needed.
template<bool FIRST>
__global__ void __launch_bounds__(1024)
passK(int sel) {
    extern __shared__ float w_lds[];          // NN floats (0 when FIRST)
    __shared__ float acc[GSZ + 8];            // +pad slot region
    const int b = blockIdx.y, g = blockIdx.x;
    const int t = threadIdx.x;                // 1024
    const float* __restrict__ wb = (sel ? g_w1 : g_w0) + b * NN;
    float* __restrict__ wn       = (sel ? g_w0 : g_w1) + b * NN;
    const int cnt = g_cnt[b * NG + g];
    const int2* __restrict__ bk = g_bucket + (size_t)(b * NG + g) * FIX + t;

    // 8 unconditional bucket loads, issued before anything else
    int2 e[KPT];
#pragma unroll
    for (int k = 0; k < KPT; ++k) e[k] = bk[k * 1024];

    if (!FIRST) {
        const float4* __restrict__ wb4 = (const float4*)wb;
        for (int i = t; i < NN / 4; i += 1024) ((float4*)w_lds)[i] = wb4[i];
    }
    if (t < GSZ + 8) acc[t] = 0.0f;
    __syncthreads();

#pragma unroll
    for (int k = 0; k < KPT; ++k)
        if (k * 1024 + t < cnt)
            unsafeAtomicAdd(&acc[e[k].y], FIRST ? 1.0f : w_lds[e[k].x]);
    __syncthreads();

    if (t < GSZ) {
        const int node = g * GSZ + t;
        if (node < NN)
            wn[node] = (FIRST ? 1.0f : w_lds[node]) + acc[t];
    }
}

// ---- final pass fused with the weighted pool of this group's rows ----
__global__ void __launch_bounds__(1024)
pass5poolK(const float* __restrict__ nodes) {
    extern __shared__ float w_lds[];          // NN floats; reused for reduction
    __shared__ float acc[GSZ + 8];
    __shared__ float w5s[GSZ];
    const int b = blockIdx.y, g = blockIdx.x;
    const int t = threadIdx.x;                // 1024
    const float* __restrict__ wb = g_w0 + b * NN;   // w4 lives in g_w0
    const int cnt = g_cnt[b * NG + g];
    const int2* __restrict__ bk = g_bucket + (size_t)(b * NG + g) * FIX + t;

    int2 e[KPT];
#pragma unroll
    for (int k = 0; k < KPT; ++k) e[k] = bk[k * 1024];

    const float4* __restrict__ wb4 = (const float4*)wb;
    for (int i = t; i < NN / 4; i += 1024) ((float4*)w_lds)[i] = wb4[i];
    if (t < GSZ + 8) acc[t] = 0.0f;
    __syncthreads();

#pragma unroll
    for (int k = 0; k < KPT; ++k)
        if (k * 1024 + t < cnt)
            unsafeAtomicAdd(&acc[e[k].y], w_lds[e[k].x]);
    __syncthreads();

    if (t < GSZ) {
        const int node = g * GSZ + t;
        w5s[t] = (node < NN) ? w_lds[node] + acc[t] : 0.0f;
    }
    __syncthreads();

    // pool: part[d] = sum_{rows in group} w5[row] * nodes[b][row][d]
    const int dslot = t & 31, rg = t >> 5;    // 32 row-threads x 32 f4-columns
    const int nbase = g * GSZ;
    const int nrows = min(GSZ, NN - nbase);   // 640 (160 for last group)
    const float4* __restrict__ base = (const float4*)(nodes + (size_t)b * NN * ND);
    float4 aA = {0.f, 0.f, 0.f, 0.f}, aB = {0.f, 0.f, 0.f, 0.f};
    int row = rg;
    for (; row + 32 < nrows; row += 64) {
        const float wA = w5s[row], wB = w5s[row + 32];
        const float4 vA = base[(size_t)(nbase + row) * 32 + dslot];
        const float4 vB = base[(size_t)(nbase + row + 32) * 32 + dslot];
        aA.x += wA * vA.x; aA.y += wA * vA.y; aA.z += wA * vA.z; aA.w += wA * vA.w;
        aB.x += wB * vB.x; aB.y += wB * vB.y; aB.z += wB * vB.z; aB.w += wB * vB.w;
    }
    if (row < nrows) {
        const float wA = w5s[row];
        const float4 vA = base[(size_t)(nbase + row) * 32 + dslot];
        aA.x += wA * vA.x; aA.y += wA * vA.y; aA.z += wA * vA.z; aA.w += wA * vA.w;
    }
    float4 s4;
    s4.x = aA.x + aB.x; s4.y = aA.y + aB.y; s4.z = aA.z + aB.z; s4.w = aA.w + aB.w;

    __syncthreads();                          // w_lds dead -> reduction buffer
    float4* red = (float4*)w_lds;
    red[t] = s4;
    __syncthreads();
    if (t < 32) {
        float4 s = red[t];
        for (int q = 1; q < 32; ++q) {
            const float4 o = red[q * 32 + t];
            s.x += o.x; s.y += o.y; s.z += o.z; s.w += o.w;
        }
        ((float4*)g_ppart)[((size_t)b * NG + g) * 32 + t] = s;
    }
}

// ---- reduce 32 partials per batch + full head, one 1024-thread block ----
__global__ void reduceHeadK(const float* __restrict__ ptype,
                            const float* __restrict__ w1, const float* __restrict__ b1,
                            const float* __restrict__ w2, const float* __restrict__ b2,
                            const float* __restrict__ w3, const float* __restrict__ b3,
                            float* __restrict__ out) {
    __shared__ float sx[NB][ND + 1];
    __shared__ float h1s[NB][80];
    __shared__ float h2s[NB][80];
    const int t = threadIdx.x;          // 1024 == NB * ND
    const int b = t >> 7, d = t & 127;

    float s = 0.0f;
    for (int j = 0; j < NG; ++j)
        s += g_ppart[(b * NG + j) * ND + d];

    float y = logf(s);
    if (isnan(y)) y = 0.0f;             // nan -> 0
    y = fmaxf(y, 0.0f);                 // relu (folds -inf -> 0)
    sx[b][d] = y;
    __syncthreads();

    if (t < NB) {
        float fm = -INFINITY;
        for (int dd = 0; dd < ND; ++dd) {
            const float v = sx[t][dd];
            if (!isinf(v)) fm = fmaxf(fm, v);
        }
        for (int dd = 0; dd < ND; ++dd)
            if (isinf(sx[t][dd])) sx[t][dd] = fm;   // +inf -> finite_max
        sx[t][ND] = ptype[t];
    }
    __syncthreads();

    if (t < NB * 80) {
        const int bb = t / 80, j = t - bb * 80;
        float v = b1[j];
        for (int k = 0; k < ND + 1; ++k) v += sx[bb][k] * w1[k * 80 + j];
        h1s[bb][j] = v > 0.0f ? v : 0.01f * v;      // leaky_relu
    }
    __syncthreads();

    if (t < NB * 80) {
        const int bb = t / 80, j = t - bb * 80;
        float v = b2[j];
        for (int k = 0; k < 80; ++k) v += h1s[bb][k] * w2[k * 80 + j];
        h2s[bb][j] = v > 0.0f ? v : 0.01f * v;
    }
    __syncthreads();

    if (t < NB * 10) {
        const int bb = t / 10, j = t - bb * 10;
        float v = b3[j];
        for (int k = 0; k < 80; ++k) v += h2s[bb][k] * w3[k * 10 + j];
        out[bb * 10 + j] = v;
    }
}

extern "C" void kernel_launch(void* const* d_in, const int* in_sizes, int n_in,
                              void* d_out, int out_size, void* d_ws, size_t ws_size,
                              hipStream_t stream) {
    const float* nodes = (const float*)d_in[0];
    const float* ptype = (const float*)d_in[1];
    const float* w1    = (const float*)d_in[2];
    const float* b1    = (const float*)d_in[3];
    const float* w2    = (const float*)d_in[4];
    const float* b2    = (const float*)d_in[5];
    const float* w3    = (const float*)d_in[6];
    const float* b3    = (const float*)d_in[7];
    const int*   edges = (const int*)d_in[8];
    float* out = (float*)d_out;

    countK<<<NB * NCHUNK, 256, 0, stream>>>(edges);
    distK<<<NB * NCHUNK, 256, 0, stream>>>(edges);

    // pass 1: w1 = 1 + A^T 1  (no staging, no init kernel)  -> writes g_w1
    passK<true><<<dim3(NG, NB), 1024, 0, stream>>>(0);
    // passes 2..4: w1->w0->w1->w0  (w4 ends in g_w0)
    passK<false><<<dim3(NG, NB), 1024, NN * sizeof(float), stream>>>(1);
    passK<false><<<dim3(NG, NB), 1024, NN * sizeof(float), stream>>>(0);
    passK<false><<<dim3(NG, NB), 1024, NN * sizeof(float), stream>>>(1);

    // pass 5 fused with the pool (w5 never materialized)
    pass5poolK<<<dim3(NG, NB), 1024, NN * sizeof(float), stream>>>(nodes);

    reduceHeadK<<<1, 1024, 0, stream>>>(ptype, w1, b1, w2, b2, w3, b3, out);
}